// Round 7
// baseline (461.606 us; speedup 1.0000x reference)
//
#include <hip/hip_runtime.h>
#include <hip/hip_bf16.h>
#include <math.h>

#define EMBED_DIM 1024
#define NUM_HEADS 16
#define HEAD_DIM  64
#define B_SZ      2
#define T_SZ      2048
#define BT        (B_SZ * T_SZ)      // 4096
#define LOG2E     1.44269504088896340736f
#define QSCALE    (0.125f * LOG2E)   // softmax scale folded with log2e into Q

typedef short bf16x8 __attribute__((ext_vector_type(8)));   // 8 bf16 in 4 VGPRs
typedef float f32x4  __attribute__((ext_vector_type(4)));

#define MFMA16(a, b, c) __builtin_amdgcn_mfma_f32_16x16x32_bf16((a), (b), (c), 0, 0, 0)

// float -> bf16 (RNE), bf16 -> float
__device__ inline short f2bf(float f) {
    unsigned u = __builtin_bit_cast(unsigned, f);
    u = (u + 0x7fffu + ((u >> 16) & 1u)) >> 16;
    return (short)u;
}
__device__ inline float bf2f(short s) {
    unsigned u = ((unsigned)(unsigned short)s) << 16;
    return __builtin_bit_cast(float, u);
}
// pack two f32 -> bf16x2 in one u32 (packed cvt when HW has it)
__device__ inline unsigned pk2(float a, float b) {
#if __has_builtin(__builtin_amdgcn_cvt_pk_bf16_f32)
    typedef __bf16 bf2_t __attribute__((ext_vector_type(2)));
    bf2_t t = __builtin_amdgcn_cvt_pk_bf16_f32(a, b);
    return __builtin_bit_cast(unsigned, t);
#else
    return (unsigned)(unsigned short)f2bf(a) | ((unsigned)(unsigned short)f2bf(b) << 16);
#endif
}

// async global->LDS, 16B per lane; lds base must be wave-uniform (lane*16 auto)
__device__ inline void gld16(const short* g, short* lds) {
    __builtin_amdgcn_global_load_lds(
        (const __attribute__((address_space(1))) void*)g,
        (__attribute__((address_space(3))) void*)lds, 16, 0, 0);
}

// swizzled frag read from a [rows][64] bf16 tile staged with chunk c at c^(r&7)
__device__ inline bf16x8 frag_swz(const short* tile, int R, int C) {
    return *(const bf16x8*)(tile + R * 64 + ((C ^ (R & 7)) << 3));
}

// direct 16B global fragment load
__device__ inline bf16x8 ld16(const short* __restrict__ g) {
    return *(const bf16x8*)g;
}

__device__ inline float red_add64(float v) {
    v += __shfl_xor(v, 1); v += __shfl_xor(v, 2); v += __shfl_xor(v, 4);
    v += __shfl_xor(v, 8); v += __shfl_xor(v, 16); v += __shfl_xor(v, 32);
    return v;
}

// ---------------------------------------------------------------------------
// K0: convert hs -> bf16.  grid 4096 x 256
// ---------------------------------------------------------------------------
__global__ __launch_bounds__(256) void cvt_in_kernel(
    const float* __restrict__ hs, short* __restrict__ hsb)
{
    const long i = ((long)blockIdx.x * 256 + threadIdx.x) * 4;
    const float4 v = *(const float4*)(hs + i);
    ushort4 o; o.x = f2bf(v.x); o.y = f2bf(v.y); o.z = f2bf(v.z); o.w = f2bf(v.w);
    *(ushort4*)(hsb + i) = o;
}

// ---------------------------------------------------------------------------
// K1: per-head weight transposes, fp32 -> bf16.
// arr 0..2: Wq/Wk/Wv [1024][64] -> [64][1024]; arr 3: Wo [64][1024] -> [1024][64]
// grid (64, 16, 4) x 256
// ---------------------------------------------------------------------------
__global__ __launch_bounds__(256) void transpose_w_kernel(
    const float* __restrict__ Wq, const float* __restrict__ Wk,
    const float* __restrict__ Wv, const float* __restrict__ Wo,
    short* __restrict__ Wqt, short* __restrict__ Wkt,
    short* __restrict__ Wvt, short* __restrict__ WoT)
{
    const int arr = blockIdx.z, h = blockIdx.y;
    const float* src; short* dst; int R, C;
    if (arr == 0)      { src = Wq; dst = Wqt; R = 1024; C = 64; }
    else if (arr == 1) { src = Wk; dst = Wkt; R = 1024; C = 64; }
    else if (arr == 2) { src = Wv; dst = Wvt; R = 1024; C = 64; }
    else               { src = Wo; dst = WoT; R = 64;   C = 1024; }
    src += (long)h * 65536; dst += (long)h * 65536;

    const int ct = C / 32;
    const int tr = blockIdx.x / ct, tc = blockIdx.x % ct;
    __shared__ float tile[32][33];
    const int tx = threadIdx.x & 31, ty = threadIdx.x >> 5;   // 32 x 8
    #pragma unroll
    for (int i = 0; i < 4; ++i) {
        const int r = ty + 8 * i;
        tile[r][tx] = src[(long)(tr * 32 + r) * C + tc * 32 + tx];
    }
    __syncthreads();
    #pragma unroll
    for (int i = 0; i < 4; ++i) {
        const int r = ty + 8 * i;
        dst[(long)(tc * 32 + r) * R + tr * 32 + tx] = f2bf(tile[tx][r]);
    }
}

// ---------------------------------------------------------------------------
// K2: fused QKV projection as ONE flat GEMM: [4096,1024] x Wt^T, Wt = [3072,1024]
// (rows n = type*1024 + h*64 + e; Wqt/Wkt/Wvt are contiguous in ws).
// grid (32, 24) x 256 (2x2 waves, 64x64/wave), BM=BN=128, BK=64.
// Epilogue decodes (type,h,e) from n: Q *QSCALE -> [b,h,t,e]; K -> [b,h,t,e];
// V -> transposed [b,h,e,t'] with the kv-permutation
// t' = (t&~63)|(t&35)|((t&12)<<1)|((t&16)>>2).
// ---------------------------------------------------------------------------
__global__ __launch_bounds__(256) void qkv_mfma_kernel(
    const short* __restrict__ hsb,
    const short* __restrict__ Wt,      // [3072][1024]
    const float* __restrict__ bq, const float* __restrict__ bk,
    const float* __restrict__ bv,
    short* __restrict__ Qb, short* __restrict__ Kb, short* __restrict__ Vtb)
{
    const int m0 = blockIdx.x * 128;
    const int n0 = blockIdx.y * 128;
    __shared__ short As[128 * 64];
    __shared__ short Bs[128 * 64];

    const int tid = threadIdx.x, lane = tid & 63, w = tid >> 6;
    const int wm = w & 1, wn = w >> 1;
    const int quad = lane >> 4, l15 = lane & 15;

    f32x4 acc[4][4] = {};

    for (int k0 = 0; k0 < 1024; k0 += 64) {
        __syncthreads();
        #pragma unroll
        for (int t = 0; t < 4; ++t) {
            const int r0 = w * 32 + t * 8;
            const int r  = r0 + (lane >> 3);
            const int cg = (lane & 7) ^ (r & 7);
            gld16(hsb + (long)(m0 + r) * 1024 + k0 + cg * 8, &As[r0 * 64]);
            gld16(Wt  + (long)(n0 + r) * 1024 + k0 + cg * 8, &Bs[r0 * 64]);
        }
        __syncthreads();
        #pragma unroll
        for (int ks = 0; ks < 2; ++ks) {
            bf16x8 af[4];
            #pragma unroll
            for (int ms = 0; ms < 4; ++ms)
                af[ms] = frag_swz(As, wm * 64 + ms * 16 + l15, ks * 4 + quad);
            #pragma unroll
            for (int ns = 0; ns < 4; ++ns) {
                const bf16x8 bfr = frag_swz(Bs, wn * 64 + ns * 16 + l15, ks * 4 + quad);
                #pragma unroll
                for (int ms = 0; ms < 4; ++ms)
                    acc[ms][ns] = MFMA16(af[ms], bfr, acc[ms][ns]);
            }
        }
    }

    // epilogue: n -> (type, h, e)
    #pragma unroll
    for (int ns = 0; ns < 4; ++ns) {
        const int n    = n0 + wn * 64 + ns * 16 + l15;
        const int type = n >> 10;          // wave-uniform
        const int h    = (n >> 6) & 15;    // wave-uniform
        const int e    = n & 63;
        const float bias = (type == 0 ? bq : type == 1 ? bk : bv)[h * 64 + e];
        #pragma unroll
        for (int ms = 0; ms < 4; ++ms) {
            const int mbase = m0 + wm * 64 + ms * 16 + quad * 4;
            const int bb = mbase >> 11, t0 = mbase & 2047;
            if (type == 2) {
                const int tp = (t0 & ~63) | (t0 & 35) | ((t0 & 12) << 1) | ((t0 & 16) >> 2);
                ushort4 pk;
                pk.x = (unsigned short)f2bf(acc[ms][ns][0] + bias);
                pk.y = (unsigned short)f2bf(acc[ms][ns][1] + bias);
                pk.z = (unsigned short)f2bf(acc[ms][ns][2] + bias);
                pk.w = (unsigned short)f2bf(acc[ms][ns][3] + bias);
                *(ushort4*)&Vtb[((long)(bb * 16 + h) * 64 + e) * 2048 + tp] = pk;
            } else {
                #pragma unroll
                for (int r = 0; r < 4; ++r) {
                    const float v = acc[ms][ns][r] + bias;
                    const long off = ((long)(bb * 16 + h) * 2048 + (t0 + r)) * 64 + e;
                    if (type == 0) Qb[off] = f2bf(v * QSCALE);
                    else           Kb[off] = f2bf(v);
                }
            }
        }
    }
}

// ---------------------------------------------------------------------------
// K3: flash attention, transposed-S, NO LDS / NO BARRIERS in the K-loop.
// K and V fragments are wave-private and contiguous in the chosen layouts, so
// they load straight global->VGPR in MFMA fragment order.  Waves run fully
// desynchronized; only vmcnt dependencies remain, so one wave's softmax VALU
// overlaps other waves' MFMA and load latency.  grid (32, 16, 2) x 256, BQ=64.
// ---------------------------------------------------------------------------
__global__ __launch_bounds__(256) void attn_mfma_kernel(
    const short* __restrict__ Qb, const short* __restrict__ Kb,
    const short* __restrict__ Vtb, const float* __restrict__ maskf,
    short* __restrict__ Ob, float* __restrict__ denomsum)
{
    const int q0 = blockIdx.x * 64;
    const int h  = blockIdx.y, b = blockIdx.z;
    const long bh = ((long)b * 16 + h) * (long)T_SZ * 64;

    __shared__ float wred[4];

    const int tid = threadIdx.x, lane = tid & 63, w = tid >> 6;
    const int quad = lane >> 4, l15 = lane & 15;
    const int qrow = q0 + w * 16 + l15;       // this lane's q row

    const short* Kg = Kb + bh;
    const short* Vg = Vtb + bh;   // [64 e][2048 t'] (kv-permuted within 64-tiles)

    // Q fragments (B-operand of K·Q^T): lane holds q-row = l15 slot
    bf16x8 qf[2];
    #pragma unroll
    for (int ks = 0; ks < 2; ++ks)
        qf[ks] = ld16(Qb + bh + (long)qrow * 64 + ks * 32 + quad * 8);

    f32x4 o[4] = {};            // O^T: row e = eb*16 + quad*4 + r, col q = l15
    float m2 = -3.0e38f;        // per-lane running max (log2 domain)
    float lp = 0.f;             // per-lane partial row sum (this quad's kv)

    const float* mrow = maskf + (long)qrow * 2048 + quad * 4;

    // per-lane fragment addresses
    const short* kbase = Kg + (long)l15 * 64 + quad * 8;          // + kv*64 + ks*32
    const short* vbase = Vg + (long)l15 * 2048 + quad * 8;        // + eb*16*2048 + kv0 + kbp*32

    for (int kt = 0; kt < 32; ++kt) {
        const int kv0 = kt * 64;

        // V fragments for this tile (consumed after softmax -> latency hidden)
        bf16x8 va[2][4];
        #pragma unroll
        for (int kbp = 0; kbp < 2; ++kbp)
            #pragma unroll
            for (int eb = 0; eb < 4; ++eb)
                va[kbp][eb] = ld16(vbase + (long)(eb * 16) * 2048 + kv0 + kbp * 32);

        // K fragments + S^T = K Q^T : s[kb] holds kv = kv0+kb*16+quad*4+r, q = l15
        f32x4 s[4] = {};
        #pragma unroll
        for (int ks = 0; ks < 2; ++ks)
            #pragma unroll
            for (int kb = 0; kb < 4; ++kb) {
                const bf16x8 kf = ld16(kbase + (long)(kv0 + kb * 16) * 64 + ks * 32);
                s[kb] = MFMA16(kf, qf[ks], s[kb]);
            }

        // + mask*log2e (fp32 mask, fma)
        #pragma unroll
        for (int kb = 0; kb < 4; ++kb) {
            const float4 mv = *(const float4*)(mrow + kv0 + kb * 16);
            s[kb][0] = fmaf(mv.x, LOG2E, s[kb][0]);
            s[kb][1] = fmaf(mv.y, LOG2E, s[kb][1]);
            s[kb][2] = fmaf(mv.z, LOG2E, s[kb][2]);
            s[kb][3] = fmaf(mv.w, LOG2E, s[kb][3]);
        }

        // online softmax (base-2), rows lane-local
        float mx = fmaxf(fmaxf(s[0][0], s[0][1]), fmaxf(s[0][2], s[0][3]));
        #pragma unroll
        for (int kb = 1; kb < 4; ++kb)
            mx = fmaxf(mx, fmaxf(fmaxf(s[kb][0], s[kb][1]), fmaxf(s[kb][2], s[kb][3])));
        mx = fmaxf(mx, __shfl_xor(mx, 16));
        mx = fmaxf(mx, __shfl_xor(mx, 32));
        const float mn = fmaxf(m2, mx);
        const float al = exp2f(m2 - mn);
        m2 = mn;
        #pragma unroll
        for (int eb = 0; eb < 4; ++eb) o[eb] *= al;
        float rs = 0.f;
        unsigned w0[4], w1[4];
        #pragma unroll
        for (int kb = 0; kb < 4; ++kb) {
            const float p0 = exp2f(s[kb][0] - mn);
            const float p1 = exp2f(s[kb][1] - mn);
            const float p2 = exp2f(s[kb][2] - mn);
            const float p3 = exp2f(s[kb][3] - mn);
            rs += (p0 + p1) + (p2 + p3);
            w0[kb] = pk2(p0, p1);
            w1[kb] = pk2(p2, p3);
        }
        lp = lp * al + rs;
        bf16x8 pb[2];
        #pragma unroll
        for (int kbp = 0; kbp < 2; ++kbp) {
            const uint4 u = {w0[2 * kbp], w1[2 * kbp], w0[2 * kbp + 1], w1[2 * kbp + 1]};
            pb[kbp] = __builtin_bit_cast(bf16x8, u);
        }

        // O^T += V^T P^T  (K=32 MFMA, custom k<->kv bijection; V pre-permuted)
        #pragma unroll
        for (int kbp = 0; kbp < 2; ++kbp)
            #pragma unroll
            for (int eb = 0; eb < 4; ++eb)
                o[eb] = MFMA16(va[kbp][eb], pb[kbp], o[eb]);
    }

    // epilogue: finish row sums, normalize, write O^T, row-norm reduction
    float lf = lp;
    lf += __shfl_xor(lf, 16);
    lf += __shfl_xor(lf, 32);
    const float inv = 1.f / lf;
    float ss = 0.f;
    #pragma unroll
    for (int eb = 0; eb < 4; ++eb) {
        o[eb] *= inv;
        #pragma unroll
        for (int r = 0; r < 4; ++r) ss += o[eb][r] * o[eb][r];
    }
    ss += __shfl_xor(ss, 16);
    ss += __shfl_xor(ss, 32);
    const float tot = sqrtf(ss);

    #pragma unroll
    for (int eb = 0; eb < 4; ++eb) {
        uint2 pk;
        pk.x = pk2(o[eb][0], o[eb][1]);
        pk.y = pk2(o[eb][2], o[eb][3]);
        *(uint2*)&Ob[((long)(b * 2048 + qrow)) * 1024 + h * 64 + eb * 16 + quad * 4] = pk;
    }
    // each row's norm appears in 4 lanes (quads): sum all, divide by 4
    const float wsum = red_add64(tot) * 0.25f;
    if (lane == 0) wred[w] = wsum;
    __syncthreads();
    if (tid == 0)
        atomicAdd(&denomsum[h], wred[0] + wred[1] + wred[2] + wred[3]);
}

// ---------------------------------------------------------------------------
// K4: scale WoT rows (per head) by g_h / (denom_h * H), in place.
// WoT regenerated by transpose_w every call -> in-place is replay-safe.
// grid 1024 x 256
// ---------------------------------------------------------------------------
__global__ __launch_bounds__(256) void scale_w_kernel(
    short* __restrict__ WoT, const float* __restrict__ denomsum,
    const float* __restrict__ gate)
{
    __shared__ float sh[16];
    if (threadIdx.x < 16) {
        const float g  = fminf(fmaxf(gate[threadIdx.x], 0.f), 1.f);
        const float dn = fmaxf(denomsum[threadIdx.x] * (1.f / (float)BT), 1e-5f);
        sh[threadIdx.x] = g / (dn * (float)NUM_HEADS);
    }
    __syncthreads();
    const long i = ((long)blockIdx.x * 256 + threadIdx.x) * 4;
    const float sc = sh[(int)(i >> 16)];
    ushort4 v = *(ushort4*)(WoT + i);
    v.x = (unsigned short)f2bf(bf2f((short)v.x) * sc);
    v.y = (unsigned short)f2bf(bf2f((short)v.y) * sc);
    v.z = (unsigned short)f2bf(bf2f((short)v.z) * sc);
    v.w = (unsigned short)f2bf(bf2f((short)v.w) * sc);
    *(ushort4*)(WoT + i) = v;
}

// ---------------------------------------------------------------------------
// K5: output projection, MFMA, double-buffered single-barrier prefetch over
// the 16 head-chunks (grid 256 blocks = 1 block/CU -> latency must be hidden
// inside the block).  BM=BN=128.
// ---------------------------------------------------------------------------
__global__ __launch_bounds__(256) void oproj_mfma_kernel(
    const short* __restrict__ Ob,    // [4096][1024] raw attention out
    const short* __restrict__ WoT,   // [16][1024][64], pre-scaled by s_h
    const float* __restrict__ bo,    // [16][1024]
    const float* __restrict__ gate,
    float* __restrict__ out)         // [4096][1024]
{
    const int m0 = blockIdx.x * 128;
    const int n0 = blockIdx.y * 128;
    __shared__ short As[2][128 * 64];
    __shared__ short Bs[2][128 * 64];

    const int tid = threadIdx.x, lane = tid & 63, w = tid >> 6;
    const int wm = w & 1, wn = w >> 1;
    const int quad = lane >> 4, l15 = lane & 15;

    auto stage = [&](int h, int buf) {
        #pragma unroll
        for (int t = 0; t < 4; ++t) {
            const int r0 = w * 32 + t * 8;
            const int r  = r0 + (lane >> 3);
            const int cg = (lane & 7) ^ (r & 7);
            gld16(Ob + (long)(m0 + r) * 1024 + h * 64 + cg * 8, &As[buf][r0 * 64]);
            gld16(WoT + (long)h * 65536 + (long)(n0 + r) * 64 + cg * 8, &Bs[buf][r0 * 64]);
        }
    };

    f32x4 acc[4][4] = {};
    stage(0, 0);

    for (int h = 0; h < 16; ++h) {
        const int cur = h & 1;
        __syncthreads();
        if (h < 15) stage(h + 1, cur ^ 1);
        #pragma unroll
        for (int ks = 0; ks < 2; ++ks) {
            bf16x8 af[4];
            #pragma unroll
            for (int ms = 0; ms < 4; ++ms)
                af[ms] = frag_swz(&As[cur][0], wm * 64 + ms * 16 + l15, ks * 4 + quad);
            #pragma unroll
            for (int ns = 0; ns < 4; ++ns) {
                const bf16x8 bfr = frag_swz(&Bs[cur][0], wn * 64 + ns * 16 + l15, ks * 4 + quad);
                #pragma unroll
                for (int ms = 0; ms < 4; ++ms)
                    acc[ms][ns] = MFMA16(af[ms], bfr, acc[ms][ns]);
            }
        }
    }

    // epilogue: bias_eff[n] = sum_h clamp(g_h)*bo[h][n]/16
    float gcl[16];
    #pragma unroll
    for (int hh = 0; hh < 16; ++hh)
        gcl[hh] = fminf(fmaxf(gate[hh], 0.f), 1.f) * (1.f / (float)NUM_HEADS);

    #pragma unroll
    for (int ns = 0; ns < 4; ++ns) {
        const int n = n0 + wn * 64 + ns * 16 + l15;
        float be = 0.f;
        #pragma unroll
        for (int hh = 0; hh < 16; ++hh) be += gcl[hh] * bo[hh * 1024 + n];
        #pragma unroll
        for (int ms = 0; ms < 4; ++ms) {
            const int m = m0 + wm * 64 + ms * 16 + quad * 4;
            #pragma unroll
            for (int r = 0; r < 4; ++r)
                out[(long)(m + r) * 1024 + n] = acc[ms][ns][r] + be;
        }
    }
}

// ---------------------------------------------------------------------------
extern "C" void kernel_launch(void* const* d_in, const int* in_sizes, int n_in,
                              void* d_out, int out_size, void* d_ws, size_t ws_size,
                              hipStream_t stream)
{
    const float* hs   = (const float*)d_in[0];
    const float* mask = (const float*)d_in[1];
    const float* Wq   = (const float*)d_in[2];
    const float* bq   = (const float*)d_in[3];
    const float* Wk   = (const float*)d_in[4];
    const float* bk   = (const float*)d_in[5];
    const float* Wv   = (const float*)d_in[6];
    const float* bv   = (const float*)d_in[7];
    const float* Wo   = (const float*)d_in[8];
    const float* bo   = (const float*)d_in[9];
    const float* gate = (const float*)d_in[10];
    float* out = (float*)d_out;

    char* ws = (char*)d_ws;
    const size_t MB = 1024 * 1024;
    short* hsb   = (short*)(ws);                 // 8 MB  (4096x1024)
    short* Wqt   = (short*)(ws + 8  * MB);       // 2 MB -- Wqt/Wkt/Wvt contiguous = Wt [3072][1024]
    short* Wkt   = (short*)(ws + 10 * MB);       // 2 MB
    short* Wvt   = (short*)(ws + 12 * MB);       // 2 MB
    short* WoT   = (short*)(ws + 14 * MB);       // 2 MB  (16x1024x64)
    short* Qb    = (short*)(ws + 16 * MB);       // 8 MB  [b,h,t,e]
    short* Kb    = (short*)(ws + 24 * MB);       // 8 MB  [b,h,t,e]
    short* Vtb   = (short*)(ws + 32 * MB);       // 8 MB  [b,h,e,t'] (kv-permuted)
    short* Ob    = (short*)(ws + 40 * MB);       // 8 MB  [b,t,h*64+e]
    float* denomsum = (float*)(ws + 48 * MB);    // 16 floats

    (void)hipMemsetAsync(denomsum, 0, NUM_HEADS * sizeof(float), stream);

    cvt_in_kernel<<<4096, 256, 0, stream>>>(hs, hsb);
    transpose_w_kernel<<<dim3(64, 16, 4), 256, 0, stream>>>(
        Wq, Wk, Wv, Wo, Wqt, Wkt, Wvt, WoT);
    qkv_mfma_kernel<<<dim3(32, 24), 256, 0, stream>>>(
        hsb, Wqt, bq, bk, bv, Qb, Kb, Vtb);
    attn_mfma_kernel<<<dim3(32, 16, 2), 256, 0, stream>>>(
        Qb, Kb, Vtb, mask, Ob, denomsum);
    scale_w_kernel<<<1024, 256, 0, stream>>>(WoT, denomsum, gate);
    oproj_mfma_kernel<<<dim3(32, 8), 256, 0, stream>>>(
        Ob, WoT, bo, gate, out);
}

// Round 8
// 292.708 us; speedup vs baseline: 1.5770x; 1.5770x over previous
//
#include <hip/hip_runtime.h>
#include <hip/hip_bf16.h>
#include <math.h>

#define EMBED_DIM 1024
#define NUM_HEADS 16
#define HEAD_DIM  64
#define B_SZ      2
#define T_SZ      2048
#define BT        (B_SZ * T_SZ)      // 4096
#define LOG2E     1.44269504088896340736f
#define QSCALE    (0.125f * LOG2E)   // softmax scale folded with log2e into Q

typedef short bf16x8 __attribute__((ext_vector_type(8)));   // 8 bf16 in 4 VGPRs
typedef float f32x4  __attribute__((ext_vector_type(4)));

#define MFMA16(a, b, c) __builtin_amdgcn_mfma_f32_16x16x32_bf16((a), (b), (c), 0, 0, 0)

// float -> bf16 (RNE), bf16 -> float
__device__ inline short f2bf(float f) {
    unsigned u = __builtin_bit_cast(unsigned, f);
    u = (u + 0x7fffu + ((u >> 16) & 1u)) >> 16;
    return (short)u;
}
__device__ inline float bf2f(short s) {
    unsigned u = ((unsigned)(unsigned short)s) << 16;
    return __builtin_bit_cast(float, u);
}
// pack two f32 -> bf16x2 in one u32 (packed cvt when HW has it)
__device__ inline unsigned pk2(float a, float b) {
#if __has_builtin(__builtin_amdgcn_cvt_pk_bf16_f32)
    typedef __bf16 bf2_t __attribute__((ext_vector_type(2)));
    bf2_t t = __builtin_amdgcn_cvt_pk_bf16_f32(a, b);
    return __builtin_bit_cast(unsigned, t);
#else
    return (unsigned)(unsigned short)f2bf(a) | ((unsigned)(unsigned short)f2bf(b) << 16);
#endif
}

// async global->LDS, 16B per lane; lds base must be wave-uniform (lane*16 auto)
__device__ inline void gld16(const short* g, short* lds) {
    __builtin_amdgcn_global_load_lds(
        (const __attribute__((address_space(1))) void*)g,
        (__attribute__((address_space(3))) void*)lds, 16, 0, 0);
}

// swizzled frag read from a [rows][64] bf16 tile staged with chunk c at c^(r&7)
__device__ inline bf16x8 frag_swz(const short* tile, int R, int C) {
    return *(const bf16x8*)(tile + R * 64 + ((C ^ (R & 7)) << 3));
}
// swizzled frag read from a [rows][128] tile (16 chunks/row, XOR on low 3 bits)
__device__ inline bf16x8 frag_swz128(const short* tile, int R, int C) {
    return *(const bf16x8*)(tile + R * 128 + (((C & 8) | ((C & 7) ^ (R & 7))) << 3));
}

__device__ inline float red_add64(float v) {
    v += __shfl_xor(v, 1); v += __shfl_xor(v, 2); v += __shfl_xor(v, 4);
    v += __shfl_xor(v, 8); v += __shfl_xor(v, 16); v += __shfl_xor(v, 32);
    return v;
}

// ---------------------------------------------------------------------------
// K0: convert hs -> bf16.  grid 4096 x 256
// ---------------------------------------------------------------------------
__global__ __launch_bounds__(256) void cvt_in_kernel(
    const float* __restrict__ hs, short* __restrict__ hsb)
{
    const long i = ((long)blockIdx.x * 256 + threadIdx.x) * 4;
    const float4 v = *(const float4*)(hs + i);
    ushort4 o; o.x = f2bf(v.x); o.y = f2bf(v.y); o.z = f2bf(v.z); o.w = f2bf(v.w);
    *(ushort4*)(hsb + i) = o;
}

// ---------------------------------------------------------------------------
// K1: per-head weight transposes, fp32 -> bf16.
// arr 0..2: Wq/Wk/Wv [1024][64] -> [64][1024]; arr 3: Wo [64][1024] -> [1024][64]
// grid (64, 16, 4) x 256
// ---------------------------------------------------------------------------
__global__ __launch_bounds__(256) void transpose_w_kernel(
    const float* __restrict__ Wq, const float* __restrict__ Wk,
    const float* __restrict__ Wv, const float* __restrict__ Wo,
    short* __restrict__ Wqt, short* __restrict__ Wkt,
    short* __restrict__ Wvt, short* __restrict__ WoT)
{
    const int arr = blockIdx.z, h = blockIdx.y;
    const float* src; short* dst; int R, C;
    if (arr == 0)      { src = Wq; dst = Wqt; R = 1024; C = 64; }
    else if (arr == 1) { src = Wk; dst = Wkt; R = 1024; C = 64; }
    else if (arr == 2) { src = Wv; dst = Wvt; R = 1024; C = 64; }
    else               { src = Wo; dst = WoT; R = 64;   C = 1024; }
    src += (long)h * 65536; dst += (long)h * 65536;

    const int ct = C / 32;
    const int tr = blockIdx.x / ct, tc = blockIdx.x % ct;
    __shared__ float tile[32][33];
    const int tx = threadIdx.x & 31, ty = threadIdx.x >> 5;   // 32 x 8
    #pragma unroll
    for (int i = 0; i < 4; ++i) {
        const int r = ty + 8 * i;
        tile[r][tx] = src[(long)(tr * 32 + r) * C + tc * 32 + tx];
    }
    __syncthreads();
    #pragma unroll
    for (int i = 0; i < 4; ++i) {
        const int r = ty + 8 * i;
        dst[(long)(tc * 32 + r) * R + tr * 32 + tx] = f2bf(tile[tx][r]);
    }
}

// ---------------------------------------------------------------------------
// K2: fused QKV projection as ONE flat GEMM: [4096,1024] x Wt^T, Wt = [3072,1024]
// (rows n = type*1024 + h*64 + e; Wqt/Wkt/Wvt are contiguous in ws).
// grid (32, 24) x 256 (2x2 waves, 64x64/wave), BM=BN=128, BK=64.
// Epilogue decodes (type,h,e) from n: Q *QSCALE -> [b,h,t,e]; K -> [b,h,t,e];
// V -> transposed [b,h,e,t'] with the kv-permutation
// t' = (t&~63)|(t&35)|((t&12)<<1)|((t&16)>>2).
// ---------------------------------------------------------------------------
__global__ __launch_bounds__(256) void qkv_mfma_kernel(
    const short* __restrict__ hsb,
    const short* __restrict__ Wt,      // [3072][1024]
    const float* __restrict__ bq, const float* __restrict__ bk,
    const float* __restrict__ bv,
    short* __restrict__ Qb, short* __restrict__ Kb, short* __restrict__ Vtb)
{
    const int m0 = blockIdx.x * 128;
    const int n0 = blockIdx.y * 128;
    __shared__ short As[128 * 64];
    __shared__ short Bs[128 * 64];

    const int tid = threadIdx.x, lane = tid & 63, w = tid >> 6;
    const int wm = w & 1, wn = w >> 1;
    const int quad = lane >> 4, l15 = lane & 15;

    f32x4 acc[4][4] = {};

    for (int k0 = 0; k0 < 1024; k0 += 64) {
        __syncthreads();
        #pragma unroll
        for (int t = 0; t < 4; ++t) {
            const int r0 = w * 32 + t * 8;
            const int r  = r0 + (lane >> 3);
            const int cg = (lane & 7) ^ (r & 7);
            gld16(hsb + (long)(m0 + r) * 1024 + k0 + cg * 8, &As[r0 * 64]);
            gld16(Wt  + (long)(n0 + r) * 1024 + k0 + cg * 8, &Bs[r0 * 64]);
        }
        __syncthreads();
        #pragma unroll
        for (int ks = 0; ks < 2; ++ks) {
            bf16x8 af[4];
            #pragma unroll
            for (int ms = 0; ms < 4; ++ms)
                af[ms] = frag_swz(As, wm * 64 + ms * 16 + l15, ks * 4 + quad);
            #pragma unroll
            for (int ns = 0; ns < 4; ++ns) {
                const bf16x8 bfr = frag_swz(Bs, wn * 64 + ns * 16 + l15, ks * 4 + quad);
                #pragma unroll
                for (int ms = 0; ms < 4; ++ms)
                    acc[ms][ns] = MFMA16(af[ms], bfr, acc[ms][ns]);
            }
        }
    }

    // epilogue: n -> (type, h, e)
    #pragma unroll
    for (int ns = 0; ns < 4; ++ns) {
        const int n    = n0 + wn * 64 + ns * 16 + l15;
        const int type = n >> 10;          // wave-uniform
        const int h    = (n >> 6) & 15;    // wave-uniform
        const int e    = n & 63;
        const float bias = (type == 0 ? bq : type == 1 ? bk : bv)[h * 64 + e];
        #pragma unroll
        for (int ms = 0; ms < 4; ++ms) {
            const int mbase = m0 + wm * 64 + ms * 16 + quad * 4;
            const int bb = mbase >> 11, t0 = mbase & 2047;
            if (type == 2) {
                const int tp = (t0 & ~63) | (t0 & 35) | ((t0 & 12) << 1) | ((t0 & 16) >> 2);
                ushort4 pk;
                pk.x = (unsigned short)f2bf(acc[ms][ns][0] + bias);
                pk.y = (unsigned short)f2bf(acc[ms][ns][1] + bias);
                pk.z = (unsigned short)f2bf(acc[ms][ns][2] + bias);
                pk.w = (unsigned short)f2bf(acc[ms][ns][3] + bias);
                *(ushort4*)&Vtb[((long)(bb * 16 + h) * 64 + e) * 2048 + tp] = pk;
            } else {
                #pragma unroll
                for (int r = 0; r < 4; ++r) {
                    const float v = acc[ms][ns][r] + bias;
                    const long off = ((long)(bb * 16 + h) * 2048 + (t0 + r)) * 64 + e;
                    if (type == 0) Qb[off] = f2bf(v * QSCALE);
                    else           Kb[off] = f2bf(v);
                }
            }
        }
    }
}

// ---------------------------------------------------------------------------
// K3: flash attention, transposed-S, KV-tile=128, two-barrier LDS staging.
// grid (32, 16, 2) x 256, BQ=64 (16 q-rows/wave).  Per 128-kv tile the softmax
// fixed costs (rescale/max/al) and barriers are amortized 2x vs KV=64.
// S init from mask (MFMA C-input), skip-rescale when running max unchanged.
// ---------------------------------------------------------------------------
__global__ __launch_bounds__(256) void attn_mfma_kernel(
    const short* __restrict__ Qb, const short* __restrict__ Kb,
    const short* __restrict__ Vtb, const float* __restrict__ maskf,
    short* __restrict__ Ob, float* __restrict__ denomsum)
{
    const int q0 = blockIdx.x * 64;
    const int h  = blockIdx.y, b = blockIdx.z;
    const long bh = ((long)b * 16 + h) * (long)T_SZ * 64;

    __shared__ short Ks[128 * 64];     // [kv 128][e 64]
    __shared__ short Vs[64 * 128];     // [e 64][t' 128]
    __shared__ float wred[4];

    const int tid = threadIdx.x, lane = tid & 63, w = tid >> 6;
    const int quad = lane >> 4, l15 = lane & 15;
    const int qrow = q0 + w * 16 + l15;       // this lane's q row

    const short* Kg = Kb + bh;
    const short* Vg = Vtb + bh;   // [64 e][2048 t'] (kv-permuted within 64-tiles)

    // Q fragments (B-operand of K·Q^T): lane holds q-row = l15 slot
    bf16x8 qf[2];
    #pragma unroll
    for (int ks = 0; ks < 2; ++ks)
        qf[ks] = *(const bf16x8*)(Qb + bh + (long)qrow * 64 + ks * 32 + quad * 8);

    f32x4 o[4] = {};            // O^T: row e = eb*16 + quad*4 + r, col q = l15
    float m2 = -3.0e38f;        // per-lane running max (log2 domain)
    float lp = 0.f;             // per-lane partial row sum (this quad's kv)

    const float* mrow = maskf + (long)qrow * 2048 + quad * 4;

    for (int kt = 0; kt < 16; ++kt) {
        const int kv0 = kt * 128;
        __syncthreads();
        // stage K tile (128x64): 4 gld16/wave, 8 rows each
        #pragma unroll
        for (int t = 0; t < 4; ++t) {
            const int r0 = w * 32 + t * 8;
            const int r  = r0 + (lane >> 3);
            const int cg = (lane & 7) ^ (r & 7);
            gld16(Kg + (long)(kv0 + r) * 64 + cg * 8, &Ks[r0 * 64]);
        }
        // stage V tile (64x128): 4 gld16/wave, 4 rows each
        #pragma unroll
        for (int t = 0; t < 4; ++t) {
            const int r0 = w * 16 + t * 4;
            const int e  = r0 + (lane >> 4);
            const int c  = lane & 15;
            const int cc = (c & 8) | ((c & 7) ^ (e & 7));
            gld16(Vg + (long)e * 2048 + kv0 + cc * 8, &Vs[r0 * 128]);
        }
        __syncthreads();

        // S^T init from mask (C-input of MFMA): s[kb] kv = kv0+kb*16+quad*4+r
        f32x4 s[8];
        #pragma unroll
        for (int kb = 0; kb < 8; ++kb) {
            const float4 mv = *(const float4*)(mrow + kv0 + kb * 16);
            s[kb][0] = mv.x * LOG2E; s[kb][1] = mv.y * LOG2E;
            s[kb][2] = mv.z * LOG2E; s[kb][3] = mv.w * LOG2E;
        }
        // S^T += K Q^T
        #pragma unroll
        for (int ks = 0; ks < 2; ++ks)
            #pragma unroll
            for (int kb = 0; kb < 8; ++kb) {
                const bf16x8 kf = frag_swz(Ks, kb * 16 + l15, ks * 4 + quad);
                s[kb] = MFMA16(kf, qf[ks], s[kb]);
            }

        // online softmax (base-2), rows lane-local
        float mx = fmaxf(fmaxf(s[0][0], s[0][1]), fmaxf(s[0][2], s[0][3]));
        #pragma unroll
        for (int kb = 1; kb < 8; ++kb)
            mx = fmaxf(mx, fmaxf(fmaxf(s[kb][0], s[kb][1]), fmaxf(s[kb][2], s[kb][3])));
        mx = fmaxf(mx, __shfl_xor(mx, 16));
        mx = fmaxf(mx, __shfl_xor(mx, 32));
        if (__any(mx > m2)) {            // wave-uniform: rescale only on new max
            const float mn = fmaxf(m2, mx);
            const float al = exp2f(m2 - mn);
            m2 = mn;
            lp *= al;
            #pragma unroll
            for (int eb = 0; eb < 4; ++eb) o[eb] *= al;
        }
        float rs = 0.f;
        unsigned w0[8], w1[8];
        #pragma unroll
        for (int kb = 0; kb < 8; ++kb) {
            const float p0 = exp2f(s[kb][0] - m2);
            const float p1 = exp2f(s[kb][1] - m2);
            const float p2 = exp2f(s[kb][2] - m2);
            const float p3 = exp2f(s[kb][3] - m2);
            rs += (p0 + p1) + (p2 + p3);
            w0[kb] = pk2(p0, p1);
            w1[kb] = pk2(p2, p3);
        }
        lp += rs;

        // O^T += V^T P^T  (4 K=32 MFMAs per o[eb]; k<->kv bijection, V pre-permuted)
        #pragma unroll
        for (int kbp = 0; kbp < 4; ++kbp) {
            const uint4 u = {w0[2 * kbp], w1[2 * kbp], w0[2 * kbp + 1], w1[2 * kbp + 1]};
            const bf16x8 pb = __builtin_bit_cast(bf16x8, u);
            #pragma unroll
            for (int eb = 0; eb < 4; ++eb) {
                const bf16x8 va = frag_swz128(Vs, eb * 16 + l15, kbp * 4 + quad);
                o[eb] = MFMA16(va, pb, o[eb]);
            }
        }
    }

    // epilogue: finish row sums, normalize, write O^T, row-norm reduction
    float lf = lp;
    lf += __shfl_xor(lf, 16);
    lf += __shfl_xor(lf, 32);
    const float inv = 1.f / lf;
    float ss = 0.f;
    #pragma unroll
    for (int eb = 0; eb < 4; ++eb) {
        o[eb] *= inv;
        #pragma unroll
        for (int r = 0; r < 4; ++r) ss += o[eb][r] * o[eb][r];
    }
    ss += __shfl_xor(ss, 16);
    ss += __shfl_xor(ss, 32);
    const float tot = sqrtf(ss);

    #pragma unroll
    for (int eb = 0; eb < 4; ++eb) {
        uint2 pk;
        pk.x = pk2(o[eb][0], o[eb][1]);
        pk.y = pk2(o[eb][2], o[eb][3]);
        *(uint2*)&Ob[((long)(b * 2048 + qrow)) * 1024 + h * 64 + eb * 16 + quad * 4] = pk;
    }
    // each row's norm appears in 4 lanes (quads): sum all, divide by 4
    const float wsum = red_add64(tot) * 0.25f;
    if (lane == 0) wred[w] = wsum;
    __syncthreads();
    if (tid == 0)
        atomicAdd(&denomsum[h], wred[0] + wred[1] + wred[2] + wred[3]);
}

// ---------------------------------------------------------------------------
// K4: scale WoT rows (per head) by g_h / (denom_h * H), in place.
// WoT regenerated by transpose_w every call -> in-place is replay-safe.
// grid 1024 x 256
// ---------------------------------------------------------------------------
__global__ __launch_bounds__(256) void scale_w_kernel(
    short* __restrict__ WoT, const float* __restrict__ denomsum,
    const float* __restrict__ gate)
{
    __shared__ float sh[16];
    if (threadIdx.x < 16) {
        const float g  = fminf(fmaxf(gate[threadIdx.x], 0.f), 1.f);
        const float dn = fmaxf(denomsum[threadIdx.x] * (1.f / (float)BT), 1e-5f);
        sh[threadIdx.x] = g / (dn * (float)NUM_HEADS);
    }
    __syncthreads();
    const long i = ((long)blockIdx.x * 256 + threadIdx.x) * 4;
    const float sc = sh[(int)(i >> 16)];
    ushort4 v = *(ushort4*)(WoT + i);
    v.x = (unsigned short)f2bf(bf2f((short)v.x) * sc);
    v.y = (unsigned short)f2bf(bf2f((short)v.y) * sc);
    v.z = (unsigned short)f2bf(bf2f((short)v.z) * sc);
    v.w = (unsigned short)f2bf(bf2f((short)v.w) * sc);
    *(ushort4*)(WoT + i) = v;
}

// ---------------------------------------------------------------------------
// K5: output projection, MFMA, double-buffered single-barrier prefetch over
// the 16 head-chunks (grid 256 blocks = 1 block/CU -> latency must be hidden
// inside the block).  BM=BN=128.
// ---------------------------------------------------------------------------
__global__ __launch_bounds__(256) void oproj_mfma_kernel(
    const short* __restrict__ Ob,    // [4096][1024] raw attention out
    const short* __restrict__ WoT,   // [16][1024][64], pre-scaled by s_h
    const float* __restrict__ bo,    // [16][1024]
    const float* __restrict__ gate,
    float* __restrict__ out)         // [4096][1024]
{
    const int m0 = blockIdx.x * 128;
    const int n0 = blockIdx.y * 128;
    __shared__ short As[2][128 * 64];
    __shared__ short Bs[2][128 * 64];

    const int tid = threadIdx.x, lane = tid & 63, w = tid >> 6;
    const int wm = w & 1, wn = w >> 1;
    const int quad = lane >> 4, l15 = lane & 15;

    auto stage = [&](int h, int buf) {
        #pragma unroll
        for (int t = 0; t < 4; ++t) {
            const int r0 = w * 32 + t * 8;
            const int r  = r0 + (lane >> 3);
            const int cg = (lane & 7) ^ (r & 7);
            gld16(Ob + (long)(m0 + r) * 1024 + h * 64 + cg * 8, &As[buf][r0 * 64]);
            gld16(WoT + (long)h * 65536 + (long)(n0 + r) * 64 + cg * 8, &Bs[buf][r0 * 64]);
        }
    };

    f32x4 acc[4][4] = {};
    stage(0, 0);

    for (int h = 0; h < 16; ++h) {
        const int cur = h & 1;
        __syncthreads();
        if (h < 15) stage(h + 1, cur ^ 1);
        #pragma unroll
        for (int ks = 0; ks < 2; ++ks) {
            bf16x8 af[4];
            #pragma unroll
            for (int ms = 0; ms < 4; ++ms)
                af[ms] = frag_swz(&As[cur][0], wm * 64 + ms * 16 + l15, ks * 4 + quad);
            #pragma unroll
            for (int ns = 0; ns < 4; ++ns) {
                const bf16x8 bfr = frag_swz(&Bs[cur][0], wn * 64 + ns * 16 + l15, ks * 4 + quad);
                #pragma unroll
                for (int ms = 0; ms < 4; ++ms)
                    acc[ms][ns] = MFMA16(af[ms], bfr, acc[ms][ns]);
            }
        }
    }

    // epilogue: bias_eff[n] = sum_h clamp(g_h)*bo[h][n]/16
    float gcl[16];
    #pragma unroll
    for (int hh = 0; hh < 16; ++hh)
        gcl[hh] = fminf(fmaxf(gate[hh], 0.f), 1.f) * (1.f / (float)NUM_HEADS);

    #pragma unroll
    for (int ns = 0; ns < 4; ++ns) {
        const int n = n0 + wn * 64 + ns * 16 + l15;
        float be = 0.f;
        #pragma unroll
        for (int hh = 0; hh < 16; ++hh) be += gcl[hh] * bo[hh * 1024 + n];
        #pragma unroll
        for (int ms = 0; ms < 4; ++ms) {
            const int m = m0 + wm * 64 + ms * 16 + quad * 4;
            #pragma unroll
            for (int r = 0; r < 4; ++r)
                out[(long)(m + r) * 1024 + n] = acc[ms][ns][r] + be;
        }
    }
}

// ---------------------------------------------------------------------------
extern "C" void kernel_launch(void* const* d_in, const int* in_sizes, int n_in,
                              void* d_out, int out_size, void* d_ws, size_t ws_size,
                              hipStream_t stream)
{
    const float* hs   = (const float*)d_in[0];
    const float* mask = (const float*)d_in[1];
    const float* Wq   = (const float*)d_in[2];
    const float* bq   = (const float*)d_in[3];
    const float* Wk   = (const float*)d_in[4];
    const float* bk   = (const float*)d_in[5];
    const float* Wv   = (const float*)d_in[6];
    const float* bv   = (const float*)d_in[7];
    const float* Wo   = (const float*)d_in[8];
    const float* bo   = (const float*)d_in[9];
    const float* gate = (const float*)d_in[10];
    float* out = (float*)d_out;

    char* ws = (char*)d_ws;
    const size_t MB = 1024 * 1024;
    short* hsb   = (short*)(ws);                 // 8 MB  (4096x1024)
    short* Wqt   = (short*)(ws + 8  * MB);       // 2 MB -- Wqt/Wkt/Wvt contiguous = Wt [3072][1024]
    short* Wkt   = (short*)(ws + 10 * MB);       // 2 MB
    short* Wvt   = (short*)(ws + 12 * MB);       // 2 MB
    short* WoT   = (short*)(ws + 14 * MB);       // 2 MB  (16x1024x64)
    short* Qb    = (short*)(ws + 16 * MB);       // 8 MB  [b,h,t,e]
    short* Kb    = (short*)(ws + 24 * MB);       // 8 MB  [b,h,t,e]
    short* Vtb   = (short*)(ws + 32 * MB);       // 8 MB  [b,h,e,t'] (kv-permuted)
    short* Ob    = (short*)(ws + 40 * MB);       // 8 MB  [b,t,h*64+e]
    float* denomsum = (float*)(ws + 48 * MB);    // 16 floats

    (void)hipMemsetAsync(denomsum, 0, NUM_HEADS * sizeof(float), stream);

    cvt_in_kernel<<<4096, 256, 0, stream>>>(hs, hsb);
    transpose_w_kernel<<<dim3(64, 16, 4), 256, 0, stream>>>(
        Wq, Wk, Wv, Wo, Wqt, Wkt, Wvt, WoT);
    qkv_mfma_kernel<<<dim3(32, 24), 256, 0, stream>>>(
        hsb, Wqt, bq, bk, bv, Qb, Kb, Vtb);
    attn_mfma_kernel<<<dim3(32, 16, 2), 256, 0, stream>>>(
        Qb, Kb, Vtb, mask, Ob, denomsum);
    scale_w_kernel<<<1024, 256, 0, stream>>>(WoT, denomsum, gate);
    oproj_mfma_kernel<<<dim3(32, 8), 256, 0, stream>>>(
        Ob, WoT, bo, gate, out);
}

// Round 9
// 263.834 us; speedup vs baseline: 1.7496x; 1.1094x over previous
//
#include <hip/hip_runtime.h>
#include <hip/hip_bf16.h>
#include <math.h>

#define EMBED_DIM 1024
#define NUM_HEADS 16
#define HEAD_DIM  64
#define B_SZ      2
#define T_SZ      2048
#define BT        (B_SZ * T_SZ)      // 4096
#define LOG2E     1.44269504088896340736f
#define QSCALE    (0.125f * LOG2E)   // softmax scale folded with log2e into Q
#define SOFT_OFF  8.0f               // fixed exp2 offset (cancels in P/l)

typedef short bf16x8 __attribute__((ext_vector_type(8)));   // 8 bf16 in 4 VGPRs
typedef float f32x4  __attribute__((ext_vector_type(4)));

#define MFMA16(a, b, c) __builtin_amdgcn_mfma_f32_16x16x32_bf16((a), (b), (c), 0, 0, 0)

// float -> bf16 (RNE), bf16 -> float
__device__ inline short f2bf(float f) {
    unsigned u = __builtin_bit_cast(unsigned, f);
    u = (u + 0x7fffu + ((u >> 16) & 1u)) >> 16;
    return (short)u;
}
__device__ inline float bf2f(short s) {
    unsigned u = ((unsigned)(unsigned short)s) << 16;
    return __builtin_bit_cast(float, u);
}
// pack two f32 -> bf16x2 in one u32 (packed cvt when HW has it)
__device__ inline unsigned pk2(float a, float b) {
#if __has_builtin(__builtin_amdgcn_cvt_pk_bf16_f32)
    typedef __bf16 bf2_t __attribute__((ext_vector_type(2)));
    bf2_t t = __builtin_amdgcn_cvt_pk_bf16_f32(a, b);
    return __builtin_bit_cast(unsigned, t);
#else
    return (unsigned)(unsigned short)f2bf(a) | ((unsigned)(unsigned short)f2bf(b) << 16);
#endif
}

// async global->LDS, 16B per lane; lds base must be wave-uniform (lane*16 auto)
__device__ inline void gld16(const short* g, short* lds) {
    __builtin_amdgcn_global_load_lds(
        (const __attribute__((address_space(1))) void*)g,
        (__attribute__((address_space(3))) void*)lds, 16, 0, 0);
}

// swizzled frag read from a [rows][64] bf16 tile staged with chunk c at c^(r&7)
__device__ inline bf16x8 frag_swz(const short* tile, int R, int C) {
    return *(const bf16x8*)(tile + R * 64 + ((C ^ (R & 7)) << 3));
}

__device__ inline float red_add64(float v) {
    v += __shfl_xor(v, 1); v += __shfl_xor(v, 2); v += __shfl_xor(v, 4);
    v += __shfl_xor(v, 8); v += __shfl_xor(v, 16); v += __shfl_xor(v, 32);
    return v;
}

// ---------------------------------------------------------------------------
// K0: convert hs -> bf16.  grid 4096 x 256
// ---------------------------------------------------------------------------
__global__ __launch_bounds__(256) void cvt_in_kernel(
    const float* __restrict__ hs, short* __restrict__ hsb)
{
    const long i = ((long)blockIdx.x * 256 + threadIdx.x) * 4;
    const float4 v = *(const float4*)(hs + i);
    ushort4 o; o.x = f2bf(v.x); o.y = f2bf(v.y); o.z = f2bf(v.z); o.w = f2bf(v.w);
    *(ushort4*)(hsb + i) = o;
}

// ---------------------------------------------------------------------------
// K1: per-head weight transposes, fp32 -> bf16.
// arr 0..2: Wq/Wk/Wv [1024][64] -> [64][1024]; arr 3: Wo [64][1024] -> [1024][64]
// grid (64, 16, 4) x 256
// ---------------------------------------------------------------------------
__global__ __launch_bounds__(256) void transpose_w_kernel(
    const float* __restrict__ Wq, const float* __restrict__ Wk,
    const float* __restrict__ Wv, const float* __restrict__ Wo,
    short* __restrict__ Wqt, short* __restrict__ Wkt,
    short* __restrict__ Wvt, short* __restrict__ WoT)
{
    const int arr = blockIdx.z, h = blockIdx.y;
    const float* src; short* dst; int R, C;
    if (arr == 0)      { src = Wq; dst = Wqt; R = 1024; C = 64; }
    else if (arr == 1) { src = Wk; dst = Wkt; R = 1024; C = 64; }
    else if (arr == 2) { src = Wv; dst = Wvt; R = 1024; C = 64; }
    else               { src = Wo; dst = WoT; R = 64;   C = 1024; }
    src += (long)h * 65536; dst += (long)h * 65536;

    const int ct = C / 32;
    const int tr = blockIdx.x / ct, tc = blockIdx.x % ct;
    __shared__ float tile[32][33];
    const int tx = threadIdx.x & 31, ty = threadIdx.x >> 5;   // 32 x 8
    #pragma unroll
    for (int i = 0; i < 4; ++i) {
        const int r = ty + 8 * i;
        tile[r][tx] = src[(long)(tr * 32 + r) * C + tc * 32 + tx];
    }
    __syncthreads();
    #pragma unroll
    for (int i = 0; i < 4; ++i) {
        const int r = ty + 8 * i;
        dst[(long)(tc * 32 + r) * R + tr * 32 + tx] = f2bf(tile[tx][r]);
    }
}

// ---------------------------------------------------------------------------
// K2: fused QKV projection as ONE flat GEMM: [4096,1024] x Wt^T, Wt = [3072,1024]
// (rows n = type*1024 + h*64 + e; Wqt/Wkt/Wvt are contiguous in ws).
// grid (32, 24) x 256 (2x2 waves, 64x64/wave), BM=BN=128, BK=64.
// Epilogue decodes (type,h,e) from n: Q *QSCALE -> [b,h,t,e]; K -> [b,h,t,e];
// V -> transposed [b,h,e,t'] with the kv-permutation
// t' = (t&~63)|(t&35)|((t&12)<<1)|((t&16)>>2).
// ---------------------------------------------------------------------------
__global__ __launch_bounds__(256) void qkv_mfma_kernel(
    const short* __restrict__ hsb,
    const short* __restrict__ Wt,      // [3072][1024]
    const float* __restrict__ bq, const float* __restrict__ bk,
    const float* __restrict__ bv,
    short* __restrict__ Qb, short* __restrict__ Kb, short* __restrict__ Vtb)
{
    const int m0 = blockIdx.x * 128;
    const int n0 = blockIdx.y * 128;
    __shared__ short As[128 * 64];
    __shared__ short Bs[128 * 64];

    const int tid = threadIdx.x, lane = tid & 63, w = tid >> 6;
    const int wm = w & 1, wn = w >> 1;
    const int quad = lane >> 4, l15 = lane & 15;

    f32x4 acc[4][4] = {};

    for (int k0 = 0; k0 < 1024; k0 += 64) {
        __syncthreads();
        #pragma unroll
        for (int t = 0; t < 4; ++t) {
            const int r0 = w * 32 + t * 8;
            const int r  = r0 + (lane >> 3);
            const int cg = (lane & 7) ^ (r & 7);
            gld16(hsb + (long)(m0 + r) * 1024 + k0 + cg * 8, &As[r0 * 64]);
            gld16(Wt  + (long)(n0 + r) * 1024 + k0 + cg * 8, &Bs[r0 * 64]);
        }
        __syncthreads();
        #pragma unroll
        for (int ks = 0; ks < 2; ++ks) {
            bf16x8 af[4];
            #pragma unroll
            for (int ms = 0; ms < 4; ++ms)
                af[ms] = frag_swz(As, wm * 64 + ms * 16 + l15, ks * 4 + quad);
            #pragma unroll
            for (int ns = 0; ns < 4; ++ns) {
                const bf16x8 bfr = frag_swz(Bs, wn * 64 + ns * 16 + l15, ks * 4 + quad);
                #pragma unroll
                for (int ms = 0; ms < 4; ++ms)
                    acc[ms][ns] = MFMA16(af[ms], bfr, acc[ms][ns]);
            }
        }
    }

    // epilogue: n -> (type, h, e)
    #pragma unroll
    for (int ns = 0; ns < 4; ++ns) {
        const int n    = n0 + wn * 64 + ns * 16 + l15;
        const int type = n >> 10;          // wave-uniform
        const int h    = (n >> 6) & 15;    // wave-uniform
        const int e    = n & 63;
        const float bias = (type == 0 ? bq : type == 1 ? bk : bv)[h * 64 + e];
        #pragma unroll
        for (int ms = 0; ms < 4; ++ms) {
            const int mbase = m0 + wm * 64 + ms * 16 + quad * 4;
            const int bb = mbase >> 11, t0 = mbase & 2047;
            if (type == 2) {
                const int tp = (t0 & ~63) | (t0 & 35) | ((t0 & 12) << 1) | ((t0 & 16) >> 2);
                ushort4 pk;
                pk.x = (unsigned short)f2bf(acc[ms][ns][0] + bias);
                pk.y = (unsigned short)f2bf(acc[ms][ns][1] + bias);
                pk.z = (unsigned short)f2bf(acc[ms][ns][2] + bias);
                pk.w = (unsigned short)f2bf(acc[ms][ns][3] + bias);
                *(ushort4*)&Vtb[((long)(bb * 16 + h) * 64 + e) * 2048 + tp] = pk;
            } else {
                #pragma unroll
                for (int r = 0; r < 4; ++r) {
                    const float v = acc[ms][ns][r] + bias;
                    const long off = ((long)(bb * 16 + h) * 2048 + (t0 + r)) * 64 + e;
                    if (type == 0) Qb[off] = f2bf(v * QSCALE);
                    else           Kb[off] = f2bf(v);
                }
            }
        }
    }
}

// ---------------------------------------------------------------------------
// K3: flash attention, transposed-S, single-buffer LDS (proven r4 structure),
// NO online max: scores for this problem are bounded (|s*log2e| << 120), so
// P = exp2(s*log2e - 8) with a FIXED offset (folded into the mask-init fma;
// the 2^-8 cancels exactly in P/l).  This deletes the per-tile max tree, the
// cross-lane shuffles and their latency stall, the rescale chain, and the
// serialization between S-MFMA and the exp block.
// grid (32, 16, 2) x 256, BQ=64 (16 q-rows/wave).
// ---------------------------------------------------------------------------
__global__ __launch_bounds__(256) void attn_mfma_kernel(
    const short* __restrict__ Qb, const short* __restrict__ Kb,
    const short* __restrict__ Vtb, const float* __restrict__ maskf,
    short* __restrict__ Ob, float* __restrict__ denomsum)
{
    const int q0 = blockIdx.x * 64;
    const int h  = blockIdx.y, b = blockIdx.z;
    const long bh = ((long)b * 16 + h) * (long)T_SZ * 64;

    __shared__ short Ks[64 * 64];
    __shared__ short Vs[64 * 64];
    __shared__ float wred[4];

    const int tid = threadIdx.x, lane = tid & 63, w = tid >> 6;
    const int quad = lane >> 4, l15 = lane & 15;
    const int qrow = q0 + w * 16 + l15;       // this lane's q row

    const short* Kg = Kb + bh;
    const short* Vg = Vtb + bh;   // [64 e][2048 t'] (kv-permuted within 64-tiles)

    // Q fragments (B-operand of K·Q^T): lane holds q-row = l15 slot
    bf16x8 qf[2];
    #pragma unroll
    for (int ks = 0; ks < 2; ++ks)
        qf[ks] = *(const bf16x8*)(Qb + bh + (long)qrow * 64 + ks * 32 + quad * 8);

    f32x4 o[4] = {};            // O^T: row e = eb*16 + quad*4 + r, col q = l15
    float lp = 0.f;             // per-lane partial row sum (this quad's kv)

    const float* mrow = maskf + (long)qrow * 2048 + quad * 4;

    for (int kt = 0; kt < 32; ++kt) {
        const int kv0 = kt * 64;

        // mask loads issue early; the vmcnt drain at the staging barrier
        // guarantees they're in regs before the MFMAs consume them as C-init
        float4 mv[4];
        #pragma unroll
        for (int kb = 0; kb < 4; ++kb)
            mv[kb] = *(const float4*)(mrow + kv0 + kb * 16);

        __syncthreads();
        #pragma unroll
        for (int t = 0; t < 2; ++t) {
            const int r0 = w * 16 + t * 8;
            const int r  = r0 + (lane >> 3);
            const int cg = (lane & 7) ^ (r & 7);
            gld16(Kg + (long)(kv0 + r) * 64 + cg * 8, &Ks[r0 * 64]);
            gld16(Vg + (long)r * 2048 + kv0 + cg * 8, &Vs[r0 * 64]);
        }
        __syncthreads();

        // S^T = K Q^T + (mask*log2e - 8) : s[kb] kv = kv0+kb*16+quad*4+r, q=l15
        f32x4 s[4];
        #pragma unroll
        for (int kb = 0; kb < 4; ++kb) {
            s[kb][0] = fmaf(mv[kb].x, LOG2E, -SOFT_OFF);
            s[kb][1] = fmaf(mv[kb].y, LOG2E, -SOFT_OFF);
            s[kb][2] = fmaf(mv[kb].z, LOG2E, -SOFT_OFF);
            s[kb][3] = fmaf(mv[kb].w, LOG2E, -SOFT_OFF);
        }
        #pragma unroll
        for (int ks = 0; ks < 2; ++ks)
            #pragma unroll
            for (int kb = 0; kb < 4; ++kb) {
                const bf16x8 kf = frag_swz(Ks, kb * 16 + l15, ks * 4 + quad);
                s[kb] = MFMA16(kf, qf[ks], s[kb]);
            }

        // P = exp2(s) directly (no max, no rescale)
        float rs = 0.f;
        unsigned w0[4], w1[4];
        #pragma unroll
        for (int kb = 0; kb < 4; ++kb) {
            const float p0 = exp2f(s[kb][0]);
            const float p1 = exp2f(s[kb][1]);
            const float p2 = exp2f(s[kb][2]);
            const float p3 = exp2f(s[kb][3]);
            rs += (p0 + p1) + (p2 + p3);
            w0[kb] = pk2(p0, p1);
            w1[kb] = pk2(p2, p3);
        }
        lp += rs;

        // O^T += V^T P^T  (K=32 MFMA, custom k<->kv bijection; V pre-permuted)
        #pragma unroll
        for (int kbp = 0; kbp < 2; ++kbp) {
            const uint4 u = {w0[2 * kbp], w1[2 * kbp], w0[2 * kbp + 1], w1[2 * kbp + 1]};
            const bf16x8 pb = __builtin_bit_cast(bf16x8, u);
            #pragma unroll
            for (int eb = 0; eb < 4; ++eb) {
                const bf16x8 va = frag_swz(Vs, eb * 16 + l15, kbp * 4 + quad);
                o[eb] = MFMA16(va, pb, o[eb]);
            }
        }
    }

    // epilogue: finish row sums, normalize, write O^T, row-norm reduction
    float lf = lp;
    lf += __shfl_xor(lf, 16);
    lf += __shfl_xor(lf, 32);
    const float inv = 1.f / lf;
    float ss = 0.f;
    #pragma unroll
    for (int eb = 0; eb < 4; ++eb) {
        o[eb] *= inv;
        #pragma unroll
        for (int r = 0; r < 4; ++r) ss += o[eb][r] * o[eb][r];
    }
    ss += __shfl_xor(ss, 16);
    ss += __shfl_xor(ss, 32);
    const float tot = sqrtf(ss);

    #pragma unroll
    for (int eb = 0; eb < 4; ++eb) {
        uint2 pk;
        pk.x = pk2(o[eb][0], o[eb][1]);
        pk.y = pk2(o[eb][2], o[eb][3]);
        *(uint2*)&Ob[((long)(b * 2048 + qrow)) * 1024 + h * 64 + eb * 16 + quad * 4] = pk;
    }
    // each row's norm appears in 4 lanes (quads): sum all, divide by 4
    const float wsum = red_add64(tot) * 0.25f;
    if (lane == 0) wred[w] = wsum;
    __syncthreads();
    if (tid == 0)
        atomicAdd(&denomsum[h], wred[0] + wred[1] + wred[2] + wred[3]);
}

// ---------------------------------------------------------------------------
// K4: scale WoT rows (per head) by g_h / (denom_h * H), in place.
// WoT regenerated by transpose_w every call -> in-place is replay-safe.
// grid 1024 x 256
// ---------------------------------------------------------------------------
__global__ __launch_bounds__(256) void scale_w_kernel(
    short* __restrict__ WoT, const float* __restrict__ denomsum,
    const float* __restrict__ gate)
{
    __shared__ float sh[16];
    if (threadIdx.x < 16) {
        const float g  = fminf(fmaxf(gate[threadIdx.x], 0.f), 1.f);
        const float dn = fmaxf(denomsum[threadIdx.x] * (1.f / (float)BT), 1e-5f);
        sh[threadIdx.x] = g / (dn * (float)NUM_HEADS);
    }
    __syncthreads();
    const long i = ((long)blockIdx.x * 256 + threadIdx.x) * 4;
    const float sc = sh[(int)(i >> 16)];
    ushort4 v = *(ushort4*)(WoT + i);
    v.x = (unsigned short)f2bf(bf2f((short)v.x) * sc);
    v.y = (unsigned short)f2bf(bf2f((short)v.y) * sc);
    v.z = (unsigned short)f2bf(bf2f((short)v.z) * sc);
    v.w = (unsigned short)f2bf(bf2f((short)v.w) * sc);
    *(ushort4*)(WoT + i) = v;
}

// ---------------------------------------------------------------------------
// K5: output projection, MFMA, double-buffered single-barrier prefetch over
// the 16 head-chunks (grid 256 blocks = 1 block/CU -> latency must be hidden
// inside the block).  BM=BN=128.
// ---------------------------------------------------------------------------
__global__ __launch_bounds__(256) void oproj_mfma_kernel(
    const short* __restrict__ Ob,    // [4096][1024] raw attention out
    const short* __restrict__ WoT,   // [16][1024][64], pre-scaled by s_h
    const float* __restrict__ bo,    // [16][1024]
    const float* __restrict__ gate,
    float* __restrict__ out)         // [4096][1024]
{
    const int m0 = blockIdx.x * 128;
    const int n0 = blockIdx.y * 128;
    __shared__ short As[2][128 * 64];
    __shared__ short Bs[2][128 * 64];

    const int tid = threadIdx.x, lane = tid & 63, w = tid >> 6;
    const int wm = w & 1, wn = w >> 1;
    const int quad = lane >> 4, l15 = lane & 15;

    auto stage = [&](int h, int buf) {
        #pragma unroll
        for (int t = 0; t < 4; ++t) {
            const int r0 = w * 32 + t * 8;
            const int r  = r0 + (lane >> 3);
            const int cg = (lane & 7) ^ (r & 7);
            gld16(Ob + (long)(m0 + r) * 1024 + h * 64 + cg * 8, &As[buf][r0 * 64]);
            gld16(WoT + (long)h * 65536 + (long)(n0 + r) * 64 + cg * 8, &Bs[buf][r0 * 64]);
        }
    };

    f32x4 acc[4][4] = {};
    stage(0, 0);

    for (int h = 0; h < 16; ++h) {
        const int cur = h & 1;
        __syncthreads();
        if (h < 15) stage(h + 1, cur ^ 1);
        #pragma unroll
        for (int ks = 0; ks < 2; ++ks) {
            bf16x8 af[4];
            #pragma unroll
            for (int ms = 0; ms < 4; ++ms)
                af[ms] = frag_swz(&As[cur][0], wm * 64 + ms * 16 + l15, ks * 4 + quad);
            #pragma unroll
            for (int ns = 0; ns < 4; ++ns) {
                const bf16x8 bfr = frag_swz(&Bs[cur][0], wn * 64 + ns * 16 + l15, ks * 4 + quad);
                #pragma unroll
                for (int ms = 0; ms < 4; ++ms)
                    acc[ms][ns] = MFMA16(af[ms], bfr, acc[ms][ns]);
            }
        }
    }

    // epilogue: bias_eff[n] = sum_h clamp(g_h)*bo[h][n]/16
    float gcl[16];
    #pragma unroll
    for (int hh = 0; hh < 16; ++hh)
        gcl[hh] = fminf(fmaxf(gate[hh], 0.f), 1.f) * (1.f / (float)NUM_HEADS);

    #pragma unroll
    for (int ns = 0; ns < 4; ++ns) {
        const int n = n0 + wn * 64 + ns * 16 + l15;
        float be = 0.f;
        #pragma unroll
        for (int hh = 0; hh < 16; ++hh) be += gcl[hh] * bo[hh * 1024 + n];
        #pragma unroll
        for (int ms = 0; ms < 4; ++ms) {
            const int m = m0 + wm * 64 + ms * 16 + quad * 4;
            #pragma unroll
            for (int r = 0; r < 4; ++r)
                out[(long)(m + r) * 1024 + n] = acc[ms][ns][r] + be;
        }
    }
}

// ---------------------------------------------------------------------------
extern "C" void kernel_launch(void* const* d_in, const int* in_sizes, int n_in,
                              void* d_out, int out_size, void* d_ws, size_t ws_size,
                              hipStream_t stream)
{
    const float* hs   = (const float*)d_in[0];
    const float* mask = (const float*)d_in[1];
    const float* Wq   = (const float*)d_in[2];
    const float* bq   = (const float*)d_in[3];
    const float* Wk   = (const float*)d_in[4];
    const float* bk   = (const float*)d_in[5];
    const float* Wv   = (const float*)d_in[6];
    const float* bv   = (const float*)d_in[7];
    const float* Wo   = (const float*)d_in[8];
    const float* bo   = (const float*)d_in[9];
    const float* gate = (const float*)d_in[10];
    float* out = (float*)d_out;

    char* ws = (char*)d_ws;
    const size_t MB = 1024 * 1024;
    short* hsb   = (short*)(ws);                 // 8 MB  (4096x1024)
    short* Wqt   = (short*)(ws + 8  * MB);       // 2 MB -- Wqt/Wkt/Wvt contiguous = Wt [3072][1024]
    short* Wkt   = (short*)(ws + 10 * MB);       // 2 MB
    short* Wvt   = (short*)(ws + 12 * MB);       // 2 MB
    short* WoT   = (short*)(ws + 14 * MB);       // 2 MB  (16x1024x64)
    short* Qb    = (short*)(ws + 16 * MB);       // 8 MB  [b,h,t,e]
    short* Kb    = (short*)(ws + 24 * MB);       // 8 MB  [b,h,t,e]
    short* Vtb   = (short*)(ws + 32 * MB);       // 8 MB  [b,h,e,t'] (kv-permuted)
    short* Ob    = (short*)(ws + 40 * MB);       // 8 MB  [b,t,h*64+e]
    float* denomsum = (float*)(ws + 48 * MB);    // 16 floats

    (void)hipMemsetAsync(denomsum, 0, NUM_HEADS * sizeof(float), stream);

    cvt_in_kernel<<<4096, 256, 0, stream>>>(hs, hsb);
    transpose_w_kernel<<<dim3(64, 16, 4), 256, 0, stream>>>(
        Wq, Wk, Wv, Wo, Wqt, Wkt, Wvt, WoT);
    qkv_mfma_kernel<<<dim3(32, 24), 256, 0, stream>>>(
        hsb, Wqt, bq, bk, bv, Qb, Kb, Vtb);
    attn_mfma_kernel<<<dim3(32, 16, 2), 256, 0, stream>>>(
        Qb, Kb, Vtb, mask, Ob, denomsum);
    scale_w_kernel<<<1024, 256, 0, stream>>>(WoT, denomsum, gate);
    oproj_mfma_kernel<<<dim3(32, 8), 256, 0, stream>>>(
        Ob, WoT, bo, gate, out);
}

// Round 10
// 260.602 us; speedup vs baseline: 1.7713x; 1.0124x over previous
//
#include <hip/hip_runtime.h>
#include <hip/hip_bf16.h>
#include <math.h>

#define EMBED_DIM 1024
#define NUM_HEADS 16
#define HEAD_DIM  64
#define B_SZ      2
#define T_SZ      2048
#define BT        (B_SZ * T_SZ)      // 4096
#define LOG2E     1.44269504088896340736f
#define QSCALE    (0.125f * LOG2E)   // softmax scale folded with log2e into Q
#define SOFT_OFF  8.0f               // fixed exp2 offset (cancels in P/l)

typedef short bf16x8 __attribute__((ext_vector_type(8)));   // 8 bf16 in 4 VGPRs
typedef float f32x4  __attribute__((ext_vector_type(4)));

#define MFMA16(a, b, c) __builtin_amdgcn_mfma_f32_16x16x32_bf16((a), (b), (c), 0, 0, 0)

// float -> bf16 (RNE), bf16 -> float
__device__ inline short f2bf(float f) {
    unsigned u = __builtin_bit_cast(unsigned, f);
    u = (u + 0x7fffu + ((u >> 16) & 1u)) >> 16;
    return (short)u;
}
__device__ inline float bf2f(short s) {
    unsigned u = ((unsigned)(unsigned short)s) << 16;
    return __builtin_bit_cast(float, u);
}
// pack two f32 -> bf16x2 in one u32 (packed cvt when HW has it)
__device__ inline unsigned pk2(float a, float b) {
#if __has_builtin(__builtin_amdgcn_cvt_pk_bf16_f32)
    typedef __bf16 bf2_t __attribute__((ext_vector_type(2)));
    bf2_t t = __builtin_amdgcn_cvt_pk_bf16_f32(a, b);
    return __builtin_bit_cast(unsigned, t);
#else
    return (unsigned)(unsigned short)f2bf(a) | ((unsigned)(unsigned short)f2bf(b) << 16);
#endif
}

// async global->LDS, 16B per lane; lds base must be wave-uniform (lane*16 auto)
__device__ inline void gld16(const short* g, short* lds) {
    __builtin_amdgcn_global_load_lds(
        (const __attribute__((address_space(1))) void*)g,
        (__attribute__((address_space(3))) void*)lds, 16, 0, 0);
}

// swizzled frag read from a [rows][64] bf16 tile staged with chunk c at c^(r&7)
__device__ inline bf16x8 frag_swz(const short* tile, int R, int C) {
    return *(const bf16x8*)(tile + R * 64 + ((C ^ (R & 7)) << 3));
}

__device__ inline float red_add64(float v) {
    v += __shfl_xor(v, 1); v += __shfl_xor(v, 2); v += __shfl_xor(v, 4);
    v += __shfl_xor(v, 8); v += __shfl_xor(v, 16); v += __shfl_xor(v, 32);
    return v;
}

// ---------------------------------------------------------------------------
// K0: convert hs -> bf16.  grid 4096 x 256
// ---------------------------------------------------------------------------
__global__ __launch_bounds__(256) void cvt_in_kernel(
    const float* __restrict__ hs, short* __restrict__ hsb)
{
    const long i = ((long)blockIdx.x * 256 + threadIdx.x) * 4;
    const float4 v = *(const float4*)(hs + i);
    ushort4 o; o.x = f2bf(v.x); o.y = f2bf(v.y); o.z = f2bf(v.z); o.w = f2bf(v.w);
    *(ushort4*)(hsb + i) = o;
}

// ---------------------------------------------------------------------------
// K1: per-head weight transposes, fp32 -> bf16.
// arr 0..2: Wq/Wk/Wv [1024][64] -> [64][1024]; arr 3: Wo [64][1024] -> [1024][64]
// grid (64, 16, 4) x 256
// ---------------------------------------------------------------------------
__global__ __launch_bounds__(256) void transpose_w_kernel(
    const float* __restrict__ Wq, const float* __restrict__ Wk,
    const float* __restrict__ Wv, const float* __restrict__ Wo,
    short* __restrict__ Wqt, short* __restrict__ Wkt,
    short* __restrict__ Wvt, short* __restrict__ WoT)
{
    const int arr = blockIdx.z, h = blockIdx.y;
    const float* src; short* dst; int R, C;
    if (arr == 0)      { src = Wq; dst = Wqt; R = 1024; C = 64; }
    else if (arr == 1) { src = Wk; dst = Wkt; R = 1024; C = 64; }
    else if (arr == 2) { src = Wv; dst = Wvt; R = 1024; C = 64; }
    else               { src = Wo; dst = WoT; R = 64;   C = 1024; }
    src += (long)h * 65536; dst += (long)h * 65536;

    const int ct = C / 32;
    const int tr = blockIdx.x / ct, tc = blockIdx.x % ct;
    __shared__ float tile[32][33];
    const int tx = threadIdx.x & 31, ty = threadIdx.x >> 5;   // 32 x 8
    #pragma unroll
    for (int i = 0; i < 4; ++i) {
        const int r = ty + 8 * i;
        tile[r][tx] = src[(long)(tr * 32 + r) * C + tc * 32 + tx];
    }
    __syncthreads();
    #pragma unroll
    for (int i = 0; i < 4; ++i) {
        const int r = ty + 8 * i;
        dst[(long)(tc * 32 + r) * R + tr * 32 + tx] = f2bf(tile[tx][r]);
    }
}

// ---------------------------------------------------------------------------
// K2: fused QKV projection as ONE flat GEMM: [4096,1024] x Wt^T, Wt = [3072,1024]
// (rows n = type*1024 + h*64 + e; Wqt/Wkt/Wvt are contiguous in ws).
// grid (32, 24) x 256 (2x2 waves, 64x64/wave), BM=BN=128, BK=64.
// Epilogue decodes (type,h,e) from n: Q *QSCALE -> [b,h,t,e]; K -> [b,h,t,e];
// V -> transposed [b,h,e,t'] with the kv-permutation
// t' = (t&~63)|(t&35)|((t&12)<<1)|((t&16)>>2).
// ---------------------------------------------------------------------------
__global__ __launch_bounds__(256) void qkv_mfma_kernel(
    const short* __restrict__ hsb,
    const short* __restrict__ Wt,      // [3072][1024]
    const float* __restrict__ bq, const float* __restrict__ bk,
    const float* __restrict__ bv,
    short* __restrict__ Qb, short* __restrict__ Kb, short* __restrict__ Vtb)
{
    const int m0 = blockIdx.x * 128;
    const int n0 = blockIdx.y * 128;
    __shared__ short As[128 * 64];
    __shared__ short Bs[128 * 64];

    const int tid = threadIdx.x, lane = tid & 63, w = tid >> 6;
    const int wm = w & 1, wn = w >> 1;
    const int quad = lane >> 4, l15 = lane & 15;

    f32x4 acc[4][4] = {};

    for (int k0 = 0; k0 < 1024; k0 += 64) {
        __syncthreads();
        #pragma unroll
        for (int t = 0; t < 4; ++t) {
            const int r0 = w * 32 + t * 8;
            const int r  = r0 + (lane >> 3);
            const int cg = (lane & 7) ^ (r & 7);
            gld16(hsb + (long)(m0 + r) * 1024 + k0 + cg * 8, &As[r0 * 64]);
            gld16(Wt  + (long)(n0 + r) * 1024 + k0 + cg * 8, &Bs[r0 * 64]);
        }
        __syncthreads();
        #pragma unroll
        for (int ks = 0; ks < 2; ++ks) {
            bf16x8 af[4];
            #pragma unroll
            for (int ms = 0; ms < 4; ++ms)
                af[ms] = frag_swz(As, wm * 64 + ms * 16 + l15, ks * 4 + quad);
            #pragma unroll
            for (int ns = 0; ns < 4; ++ns) {
                const bf16x8 bfr = frag_swz(Bs, wn * 64 + ns * 16 + l15, ks * 4 + quad);
                #pragma unroll
                for (int ms = 0; ms < 4; ++ms)
                    acc[ms][ns] = MFMA16(af[ms], bfr, acc[ms][ns]);
            }
        }
    }

    // epilogue: n -> (type, h, e)
    #pragma unroll
    for (int ns = 0; ns < 4; ++ns) {
        const int n    = n0 + wn * 64 + ns * 16 + l15;
        const int type = n >> 10;          // wave-uniform
        const int h    = (n >> 6) & 15;    // wave-uniform
        const int e    = n & 63;
        const float bias = (type == 0 ? bq : type == 1 ? bk : bv)[h * 64 + e];
        #pragma unroll
        for (int ms = 0; ms < 4; ++ms) {
            const int mbase = m0 + wm * 64 + ms * 16 + quad * 4;
            const int bb = mbase >> 11, t0 = mbase & 2047;
            if (type == 2) {
                const int tp = (t0 & ~63) | (t0 & 35) | ((t0 & 12) << 1) | ((t0 & 16) >> 2);
                ushort4 pk;
                pk.x = (unsigned short)f2bf(acc[ms][ns][0] + bias);
                pk.y = (unsigned short)f2bf(acc[ms][ns][1] + bias);
                pk.z = (unsigned short)f2bf(acc[ms][ns][2] + bias);
                pk.w = (unsigned short)f2bf(acc[ms][ns][3] + bias);
                *(ushort4*)&Vtb[((long)(bb * 16 + h) * 64 + e) * 2048 + tp] = pk;
            } else {
                #pragma unroll
                for (int r = 0; r < 4; ++r) {
                    const float v = acc[ms][ns][r] + bias;
                    const long off = ((long)(bb * 16 + h) * 2048 + (t0 + r)) * 64 + e;
                    if (type == 0) Qb[off] = f2bf(v * QSCALE);
                    else           Kb[off] = f2bf(v);
                }
            }
        }
    }
}

// ---------------------------------------------------------------------------
// K3: flash attention, transposed-S, no-max softmax (fixed exp2 offset),
// kv-outer / q-inner: each wave owns TWO 16-row q-subtiles (BQ=128/block),
// so each staged K/V tile is amortized over 2x MFMA+softmax work and the
// per-CU convoy count halves (2 blocks/CU x 32 kt).  grid (16, 16, 2) x 256.
// ---------------------------------------------------------------------------
__global__ __launch_bounds__(256) void attn_mfma_kernel(
    const short* __restrict__ Qb, const short* __restrict__ Kb,
    const short* __restrict__ Vtb, const float* __restrict__ maskf,
    short* __restrict__ Ob, float* __restrict__ denomsum)
{
    const int q0 = blockIdx.x * 128;
    const int h  = blockIdx.y, b = blockIdx.z;
    const long bh = ((long)b * 16 + h) * (long)T_SZ * 64;

    __shared__ short Ks[64 * 64];
    __shared__ short Vs[64 * 64];
    __shared__ float wred[4];

    const int tid = threadIdx.x, lane = tid & 63, w = tid >> 6;
    const int quad = lane >> 4, l15 = lane & 15;
    const int qrowA = q0 + w * 32 + l15;      // qs=0 row; qs=1 is +16

    const short* Kg = Kb + bh;
    const short* Vg = Vtb + bh;   // [64 e][2048 t'] (kv-permuted within 64-tiles)

    // Q fragments (B-operand of K·Q^T), 2 q-subtiles per wave
    bf16x8 qf[2][2];
    #pragma unroll
    for (int qs = 0; qs < 2; ++qs)
        #pragma unroll
        for (int ks = 0; ks < 2; ++ks)
            qf[qs][ks] = *(const bf16x8*)(Qb + bh +
                (long)(qrowA + qs * 16) * 64 + ks * 32 + quad * 8);

    f32x4 o[2][4] = {};         // O^T per qs: row e = eb*16+quad*4+r, col q
    float lp[2] = {0.f, 0.f};   // per-lane partial row sums

    const float* mrowA = maskf + (long)qrowA * 2048 + quad * 4;

    for (int kt = 0; kt < 32; ++kt) {
        const int kv0 = kt * 64;

        // mask loads issue early; the vmcnt drain at the staging barrier
        // guarantees they're in regs before the MFMAs consume them as C-init
        float4 mv[2][4];
        #pragma unroll
        for (int qs = 0; qs < 2; ++qs)
            #pragma unroll
            for (int kb = 0; kb < 4; ++kb)
                mv[qs][kb] = *(const float4*)(mrowA + (long)qs * 16 * 2048 + kv0 + kb * 16);

        __syncthreads();
        #pragma unroll
        for (int t = 0; t < 2; ++t) {
            const int r0 = w * 16 + t * 8;
            const int r  = r0 + (lane >> 3);
            const int cg = (lane & 7) ^ (r & 7);
            gld16(Kg + (long)(kv0 + r) * 64 + cg * 8, &Ks[r0 * 64]);
            gld16(Vg + (long)r * 2048 + kv0 + cg * 8, &Vs[r0 * 64]);
        }
        __syncthreads();

        #pragma unroll
        for (int qs = 0; qs < 2; ++qs) {
            // S^T = K Q^T + (mask*log2e - 8)
            f32x4 s[4];
            #pragma unroll
            for (int kb = 0; kb < 4; ++kb) {
                s[kb][0] = fmaf(mv[qs][kb].x, LOG2E, -SOFT_OFF);
                s[kb][1] = fmaf(mv[qs][kb].y, LOG2E, -SOFT_OFF);
                s[kb][2] = fmaf(mv[qs][kb].z, LOG2E, -SOFT_OFF);
                s[kb][3] = fmaf(mv[qs][kb].w, LOG2E, -SOFT_OFF);
            }
            #pragma unroll
            for (int ks = 0; ks < 2; ++ks)
                #pragma unroll
                for (int kb = 0; kb < 4; ++kb) {
                    const bf16x8 kf = frag_swz(Ks, kb * 16 + l15, ks * 4 + quad);
                    s[kb] = MFMA16(kf, qf[qs][ks], s[kb]);
                }

            // P = exp2(s) directly (no max, no rescale)
            float rs = 0.f;
            unsigned w0[4], w1[4];
            #pragma unroll
            for (int kb = 0; kb < 4; ++kb) {
                const float p0 = exp2f(s[kb][0]);
                const float p1 = exp2f(s[kb][1]);
                const float p2 = exp2f(s[kb][2]);
                const float p3 = exp2f(s[kb][3]);
                rs += (p0 + p1) + (p2 + p3);
                w0[kb] = pk2(p0, p1);
                w1[kb] = pk2(p2, p3);
            }
            lp[qs] += rs;

            // O^T += V^T P^T  (K=32 MFMA, k<->kv bijection; V pre-permuted)
            #pragma unroll
            for (int kbp = 0; kbp < 2; ++kbp) {
                const uint4 u = {w0[2 * kbp], w1[2 * kbp], w0[2 * kbp + 1], w1[2 * kbp + 1]};
                const bf16x8 pb = __builtin_bit_cast(bf16x8, u);
                #pragma unroll
                for (int eb = 0; eb < 4; ++eb) {
                    const bf16x8 va = frag_swz(Vs, eb * 16 + l15, kbp * 4 + quad);
                    o[qs][eb] = MFMA16(va, pb, o[qs][eb]);
                }
            }
        }
    }

    // epilogue: finish row sums, normalize, write O^T, row-norm reduction
    float tot = 0.f;
    #pragma unroll
    for (int qs = 0; qs < 2; ++qs) {
        float lf = lp[qs];
        lf += __shfl_xor(lf, 16);
        lf += __shfl_xor(lf, 32);
        const float inv = 1.f / lf;
        float ss = 0.f;
        #pragma unroll
        for (int eb = 0; eb < 4; ++eb) {
            o[qs][eb] *= inv;
            #pragma unroll
            for (int r = 0; r < 4; ++r) ss += o[qs][eb][r] * o[qs][eb][r];
        }
        ss += __shfl_xor(ss, 16);
        ss += __shfl_xor(ss, 32);
        tot += sqrtf(ss);

        const int qrow = qrowA + qs * 16;
        #pragma unroll
        for (int eb = 0; eb < 4; ++eb) {
            uint2 pk;
            pk.x = pk2(o[qs][eb][0], o[qs][eb][1]);
            pk.y = pk2(o[qs][eb][2], o[qs][eb][3]);
            *(uint2*)&Ob[((long)(b * 2048 + qrow)) * 1024 + h * 64 + eb * 16 + quad * 4] = pk;
        }
    }
    // each row's norm appears in 4 lanes (quads): sum all, divide by 4
    const float wsum = red_add64(tot) * 0.25f;
    if (lane == 0) wred[w] = wsum;
    __syncthreads();
    if (tid == 0)
        atomicAdd(&denomsum[h], wred[0] + wred[1] + wred[2] + wred[3]);
}

// ---------------------------------------------------------------------------
// K4: scale WoT rows (per head) by g_h / (denom_h * H), in place.
// WoT regenerated by transpose_w every call -> in-place is replay-safe.
// grid 1024 x 256
// ---------------------------------------------------------------------------
__global__ __launch_bounds__(256) void scale_w_kernel(
    short* __restrict__ WoT, const float* __restrict__ denomsum,
    const float* __restrict__ gate)
{
    __shared__ float sh[16];
    if (threadIdx.x < 16) {
        const float g  = fminf(fmaxf(gate[threadIdx.x], 0.f), 1.f);
        const float dn = fmaxf(denomsum[threadIdx.x] * (1.f / (float)BT), 1e-5f);
        sh[threadIdx.x] = g / (dn * (float)NUM_HEADS);
    }
    __syncthreads();
    const long i = ((long)blockIdx.x * 256 + threadIdx.x) * 4;
    const float sc = sh[(int)(i >> 16)];
    ushort4 v = *(ushort4*)(WoT + i);
    v.x = (unsigned short)f2bf(bf2f((short)v.x) * sc);
    v.y = (unsigned short)f2bf(bf2f((short)v.y) * sc);
    v.z = (unsigned short)f2bf(bf2f((short)v.z) * sc);
    v.w = (unsigned short)f2bf(bf2f((short)v.w) * sc);
    *(ushort4*)(WoT + i) = v;
}

// ---------------------------------------------------------------------------
// K5: output projection, MFMA, double-buffered single-barrier prefetch over
// the 16 head-chunks (grid 256 blocks = 1 block/CU -> latency must be hidden
// inside the block).  BM=BN=128.
// ---------------------------------------------------------------------------
__global__ __launch_bounds__(256) void oproj_mfma_kernel(
    const short* __restrict__ Ob,    // [4096][1024] raw attention out
    const short* __restrict__ WoT,   // [16][1024][64], pre-scaled by s_h
    const float* __restrict__ bo,    // [16][1024]
    const float* __restrict__ gate,
    float* __restrict__ out)         // [4096][1024]
{
    const int m0 = blockIdx.x * 128;
    const int n0 = blockIdx.y * 128;
    __shared__ short As[2][128 * 64];
    __shared__ short Bs[2][128 * 64];

    const int tid = threadIdx.x, lane = tid & 63, w = tid >> 6;
    const int wm = w & 1, wn = w >> 1;
    const int quad = lane >> 4, l15 = lane & 15;

    auto stage = [&](int h, int buf) {
        #pragma unroll
        for (int t = 0; t < 4; ++t) {
            const int r0 = w * 32 + t * 8;
            const int r  = r0 + (lane >> 3);
            const int cg = (lane & 7) ^ (r & 7);
            gld16(Ob + (long)(m0 + r) * 1024 + h * 64 + cg * 8, &As[buf][r0 * 64]);
            gld16(WoT + (long)h * 65536 + (long)(n0 + r) * 64 + cg * 8, &Bs[buf][r0 * 64]);
        }
    };

    f32x4 acc[4][4] = {};
    stage(0, 0);

    for (int h = 0; h < 16; ++h) {
        const int cur = h & 1;
        __syncthreads();
        if (h < 15) stage(h + 1, cur ^ 1);
        #pragma unroll
        for (int ks = 0; ks < 2; ++ks) {
            bf16x8 af[4];
            #pragma unroll
            for (int ms = 0; ms < 4; ++ms)
                af[ms] = frag_swz(&As[cur][0], wm * 64 + ms * 16 + l15, ks * 4 + quad);
            #pragma unroll
            for (int ns = 0; ns < 4; ++ns) {
                const bf16x8 bfr = frag_swz(&Bs[cur][0], wn * 64 + ns * 16 + l15, ks * 4 + quad);
                #pragma unroll
                for (int ms = 0; ms < 4; ++ms)
                    acc[ms][ns] = MFMA16(af[ms], bfr, acc[ms][ns]);
            }
        }
    }

    // epilogue: bias_eff[n] = sum_h clamp(g_h)*bo[h][n]/16
    float gcl[16];
    #pragma unroll
    for (int hh = 0; hh < 16; ++hh)
        gcl[hh] = fminf(fmaxf(gate[hh], 0.f), 1.f) * (1.f / (float)NUM_HEADS);

    #pragma unroll
    for (int ns = 0; ns < 4; ++ns) {
        const int n = n0 + wn * 64 + ns * 16 + l15;
        float be = 0.f;
        #pragma unroll
        for (int hh = 0; hh < 16; ++hh) be += gcl[hh] * bo[hh * 1024 + n];
        #pragma unroll
        for (int ms = 0; ms < 4; ++ms) {
            const int m = m0 + wm * 64 + ms * 16 + quad * 4;
            #pragma unroll
            for (int r = 0; r < 4; ++r)
                out[(long)(m + r) * 1024 + n] = acc[ms][ns][r] + be;
        }
    }
}

// ---------------------------------------------------------------------------
extern "C" void kernel_launch(void* const* d_in, const int* in_sizes, int n_in,
                              void* d_out, int out_size, void* d_ws, size_t ws_size,
                              hipStream_t stream)
{
    const float* hs   = (const float*)d_in[0];
    const float* mask = (const float*)d_in[1];
    const float* Wq   = (const float*)d_in[2];
    const float* bq   = (const float*)d_in[3];
    const float* Wk   = (const float*)d_in[4];
    const float* bk   = (const float*)d_in[5];
    const float* Wv   = (const float*)d_in[6];
    const float* bv   = (const float*)d_in[7];
    const float* Wo   = (const float*)d_in[8];
    const float* bo   = (const float*)d_in[9];
    const float* gate = (const float*)d_in[10];
    float* out = (float*)d_out;

    char* ws = (char*)d_ws;
    const size_t MB = 1024 * 1024;
    short* hsb   = (short*)(ws);                 // 8 MB  (4096x1024)
    short* Wqt   = (short*)(ws + 8  * MB);       // 2 MB -- Wqt/Wkt/Wvt contiguous = Wt [3072][1024]
    short* Wkt   = (short*)(ws + 10 * MB);       // 2 MB
    short* Wvt   = (short*)(ws + 12 * MB);       // 2 MB
    short* WoT   = (short*)(ws + 14 * MB);       // 2 MB  (16x1024x64)
    short* Qb    = (short*)(ws + 16 * MB);       // 8 MB  [b,h,t,e]
    short* Kb    = (short*)(ws + 24 * MB);       // 8 MB  [b,h,t,e]
    short* Vtb   = (short*)(ws + 32 * MB);       // 8 MB  [b,h,e,t'] (kv-permuted)
    short* Ob    = (short*)(ws + 40 * MB);       // 8 MB  [b,t,h*64+e]
    float* denomsum = (float*)(ws + 48 * MB);    // 16 floats

    (void)hipMemsetAsync(denomsum, 0, NUM_HEADS * sizeof(float), stream);

    cvt_in_kernel<<<4096, 256, 0, stream>>>(hs, hsb);
    transpose_w_kernel<<<dim3(64, 16, 4), 256, 0, stream>>>(
        Wq, Wk, Wv, Wo, Wqt, Wkt, Wvt, WoT);
    qkv_mfma_kernel<<<dim3(32, 24), 256, 0, stream>>>(
        hsb, Wqt, bq, bk, bv, Qb, Kb, Vtb);
    attn_mfma_kernel<<<dim3(16, 16, 2), 256, 0, stream>>>(
        Qb, Kb, Vtb, mask, Ob, denomsum);
    scale_w_kernel<<<1024, 256, 0, stream>>>(WoT, denomsum, gate);
    oproj_mfma_kernel<<<dim3(32, 8), 256, 0, stream>>>(
        Ob, WoT, bo, gate, out);
}